// Round 9
// baseline (982.419 us; speedup 1.0000x reference)
//
#include <hip/hip_runtime.h>

#define EPS_LN 1e-5f
typedef unsigned int uint;

using bf16x8 = __attribute__((ext_vector_type(8))) short;
using f32x4  = __attribute__((ext_vector_type(4))) float;

__device__ inline float bf2f(ushort h){ return __uint_as_float(((uint)h) << 16); }
__device__ inline ushort f2bf(float f){
  uint u = __float_as_uint(f);
  u += 0x7fffu + ((u >> 16) & 1u);   // round-to-nearest-even
  return (ushort)(u >> 16);
}

// ---------------- CSR build (dst-indexed) ----------------
__global__ void k_deg(const int* __restrict__ ei, int* __restrict__ deg, int E, int N){
  int e = blockIdx.x * 256 + threadIdx.x;
  if (e >= E + N) return;
  int dst = (e < E) ? ei[E + e] : (e - E);   // self loops appended
  atomicAdd(&deg[dst], 1);
}

__global__ __launch_bounds__(1024) void k_bsum(const int* __restrict__ deg, int* __restrict__ bsum, int n){
  __shared__ int ws[16];
  const int t = (int)threadIdx.x, lane = t & 63, w = t >> 6;
  int i = blockIdx.x * 1024 + t;
  int v = (i < n) ? deg[i] : 0;
  #pragma unroll
  for (int off = 32; off; off >>= 1) v += __shfl_xor(v, off);
  if (lane == 0) ws[w] = v;
  __syncthreads();
  if (t == 0){
    int s = 0;
    #pragma unroll
    for (int k = 0; k < 16; k++) s += ws[k];
    bsum[blockIdx.x] = s;
  }
}

// block 0: exclusive scan of block sums; block 1: graph bounds binary search
__global__ __launch_bounds__(256) void k_misc(int* __restrict__ bsum, int nb,
                                              const int* __restrict__ batch, int* __restrict__ pos,
                                              int N, int G){
  const int t = (int)threadIdx.x;
  if (blockIdx.x == 0){
    if (t >= 64) return;
    const int lane = t;
    int carry = 0;
    for (int b0 = 0; b0 < nb; b0 += 64){
      int i = b0 + lane;
      int v = (i < nb) ? bsum[i] : 0;
      int s = v;
      #pragma unroll
      for (int off = 1; off < 64; off <<= 1){ int u = __shfl_up(s, off); if (lane >= off) s += u; }
      if (i < nb) bsum[i] = s - v + carry;   // exclusive
      carry += __shfl(s, 63);
    }
  } else {
    int g = t;
    if (g > G) return;
    int lo = 0, hi = N;
    while (lo < hi){
      int mid = (lo + hi) >> 1;
      if (batch[mid] < g) lo = mid + 1; else hi = mid;
    }
    pos[g] = lo;
  }
}

__global__ __launch_bounds__(1024) void k_scan2(const int* __restrict__ deg, const int* __restrict__ bpre,
                                                int* __restrict__ row_ptr, int* __restrict__ cursor, int n){
  __shared__ int wsum[16];
  const int t = (int)threadIdx.x, lane = t & 63, w = t >> 6;
  int i = blockIdx.x * 1024 + t;
  int v = (i < n) ? deg[i] : 0;
  int s = v;
  #pragma unroll
  for (int off = 1; off < 64; off <<= 1){ int u = __shfl_up(s, off); if (lane >= off) s += u; }
  if (lane == 63) wsum[w] = s;
  __syncthreads();
  if (w == 0 && lane < 16){
    int sc = wsum[lane];
    #pragma unroll
    for (int off = 1; off < 16; off <<= 1){ int u = __shfl_up(sc, off); if (lane >= off) sc += u; }
    wsum[lane] = sc;
  }
  __syncthreads();
  int prefix = bpre[blockIdx.x] + (w ? wsum[w - 1] : 0) + s;   // inclusive
  if (i < n){ row_ptr[i + 1] = prefix; cursor[i] = prefix - v; }
  if (i == 0) row_ptr[0] = 0;
}

__global__ void k_scatter(const int* __restrict__ ei, int* __restrict__ cursor,
                          int* __restrict__ csr_src, int E, int N){
  int e = blockIdx.x * 256 + threadIdx.x;
  if (e >= E + N) return;
  int src, dst;
  if (e < E){ src = ei[e]; dst = ei[E + e]; } else { src = dst = e - E; }
  int pos = atomicAdd(&cursor[dst], 1);
  csr_src[pos] = src;
}

// ---------------- combined dtype prep: cast x + transpose/cast 3 weights ----------------
__global__ void k_prep(const float* __restrict__ x, ushort* __restrict__ x_bf,
                       const float* __restrict__ W1, ushort* __restrict__ W1t,
                       const float* __restrict__ W2, ushort* __restrict__ W2t,
                       const float* __restrict__ W3, ushort* __restrict__ W3t, int N){
  int i = blockIdx.x * 256 + threadIdx.x;
  const int c0 = N * 32;                    // float4 quads of x
  if (i < c0){
    float4 v = reinterpret_cast<const float4*>(x)[i];
    ushort4 o; o.x = f2bf(v.x); o.y = f2bf(v.y); o.z = f2bf(v.z); o.w = f2bf(v.w);
    reinterpret_cast<ushort4*>(x_bf)[i] = o;
    return;
  }
  i -= c0;
  if (i < 256 * 128){                       // W1t[n*128+k] = W1[k*256+n]
    int n = i >> 7, k = i & 127;
    W1t[i] = f2bf(W1[(size_t)k * 256 + n]);
    return;
  }
  i -= 256 * 128;
  if (i < 256 * 256){                       // W2t[n*256+k] = W2[k*256+n]
    int n = i >> 8, k = i & 255;
    W2t[i] = f2bf(W2[(size_t)k * 256 + n]);
    return;
  }
  i -= 256 * 256;
  if (i < 128 * 256){                       // W3t[n*256+k] = W3[k*128+n]
    int n = i >> 8, k = i & 255;
    W3t[i] = f2bf(W3[(size_t)k * 128 + n]);
  }
}

// ---------------- MFMA GEMM + fused attention-coef epilogue, SLICED output layout ----------
// xls[slice][node][SC] (bf16) = A[M,K](bf16) @ Wt[N,K](bf16)^T, column-sliced for XCD-L2 pinning
template<int K, int N, int H, int SC>
__global__ __launch_bounds__(256, 2) void k_mm(const ushort* __restrict__ A,
                                               const ushort* __restrict__ Wt,
                                               ushort* __restrict__ xls,
                                               const float* __restrict__ asrc,
                                               const float* __restrict__ adst,
                                               float* __restrict__ al, float* __restrict__ ar,
                                               int M)
{
  constexpr int BANDS = (N / H) / 64;   // 64-col bands per head: 1 (H=4) or 2 (H=1)
  constexpr int LOG2SC = (SC == 32) ? 5 : 4;
  __shared__ __align__(16) ushort ldsA[128 * 128];
  __shared__ __align__(16) ushort ldsB[128 * 128];

  const int t = (int)threadIdx.x;
  const int lane = t & 63;
  const int w = t >> 6;
  const int wm = w >> 1, wn = w & 1;
  const int row0 = blockIdx.x * 128;
  const int n0 = blockIdx.y * 128;
  const int trow = t >> 4;     // 0..15
  const int tk = t & 15;       // kb8 index

  f32x4 acc[4][4];
  #pragma unroll
  for (int mt = 0; mt < 4; mt++)
    #pragma unroll
    for (int nt = 0; nt < 4; nt++)
      acc[mt][nt] = (f32x4){0.f, 0.f, 0.f, 0.f};

  #pragma unroll
  for (int kt = 0; kt < K / 128; kt++){
    uint4 ra[8], rb[8];
    #pragma unroll
    for (int p = 0; p < 8; p++){
      int arow = p * 16 + trow;
      int grow = row0 + arow; if (grow > M - 1) grow = M - 1;
      ra[p] = *reinterpret_cast<const uint4*>(&A[(size_t)grow * K + kt * 128 + tk * 8]);
      rb[p] = *reinterpret_cast<const uint4*>(&Wt[(size_t)(n0 + arow) * K + kt * 128 + tk * 8]);
    }
    if (kt) __syncthreads();          // previous tile fully consumed
    #pragma unroll
    for (int p = 0; p < 8; p++){
      int arow = p * 16 + trow;
      int sw = (tk ^ (arow & 7)) * 8;
      *reinterpret_cast<uint4*>(&ldsA[arow * 128 + sw]) = ra[p];
      *reinterpret_cast<uint4*>(&ldsB[arow * 128 + sw]) = rb[p];
    }
    __syncthreads();

    #pragma unroll
    for (int ks = 0; ks < 4; ks++){
      bf16x8 af[4], bfr[4];
      const int kb8 = ks * 4 + (lane >> 4);
      #pragma unroll
      for (int mt = 0; mt < 4; mt++){
        int arow = wm * 64 + mt * 16 + (lane & 15);
        af[mt] = *reinterpret_cast<const bf16x8*>(&ldsA[arow * 128 + ((kb8 ^ (arow & 7)) * 8)]);
        int brow = wn * 64 + mt * 16 + (lane & 15);
        bfr[mt] = *reinterpret_cast<const bf16x8*>(&ldsB[brow * 128 + ((kb8 ^ (brow & 7)) * 8)]);
      }
      #pragma unroll
      for (int mt = 0; mt < 4; mt++)
        #pragma unroll
        for (int nt = 0; nt < 4; nt++)
          acc[mt][nt] = __builtin_amdgcn_mfma_f32_16x16x32_bf16(af[mt], bfr[nt], acc[mt][nt], 0, 0, 0);
    }
  }

  // ---- epilogue 1: sliced store (C/D map col=lane&15, row=(lane>>4)*4+r, m89-verified) ----
  #pragma unroll
  for (int mt = 0; mt < 4; mt++){
    const int grow_b = row0 + wm * 64 + mt * 16 + (lane >> 4) * 4;
    #pragma unroll
    for (int nt = 0; nt < 4; nt++){
      const int gcol = n0 + wn * 64 + nt * 16 + (lane & 15);
      const size_t sbase = ((size_t)(gcol >> LOG2SC) * M) * SC + (gcol & (SC - 1));
      #pragma unroll
      for (int r = 0; r < 4; r++){
        int grow = grow_b + r;
        if (grow < M) xls[sbase + (size_t)grow * SC] = f2bf(acc[mt][nt][r]);
      }
    }
  }

  // ---- epilogue 2: fused attention coefficients from f32 accumulators ----
  float av[4], bv[4];
  #pragma unroll
  for (int nt = 0; nt < 4; nt++){
    int col = n0 + wn * 64 + nt * 16 + (lane & 15);
    av[nt] = asrc[col]; bv[nt] = adst[col];
  }
  float paA[4][4], pbA[4][4];     // [mt][r], reduced over the 64-col band
  #pragma unroll
  for (int mt = 0; mt < 4; mt++){
    #pragma unroll
    for (int r = 0; r < 4; r++){
      float pa = acc[mt][0][r] * av[0] + acc[mt][1][r] * av[1]
               + acc[mt][2][r] * av[2] + acc[mt][3][r] * av[3];
      float pb = acc[mt][0][r] * bv[0] + acc[mt][1][r] * bv[1]
               + acc[mt][2][r] * bv[2] + acc[mt][3][r] * bv[3];
      #pragma unroll
      for (int off = 1; off < 16; off <<= 1){ pa += __shfl_xor(pa, off); pb += __shfl_xor(pb, off); }
      paA[mt][r] = pa; pbA[mt][r] = pb;
    }
  }
  if constexpr (BANDS == 1){
    const int h = (n0 + wn * 64) / (N / H);
    if ((lane & 15) == 0){
      #pragma unroll
      for (int mt = 0; mt < 4; mt++){
        #pragma unroll
        for (int r = 0; r < 4; r++){
          int row = row0 + wm * 64 + mt * 16 + (lane >> 4) * 4 + r;
          if (row < M){
            al[(size_t)row * H + h] = paA[mt][r];
            ar[(size_t)row * H + h] = pbA[mt][r];
          }
        }
      }
    }
  } else {
    // H=1: two column bands (wn=0,1) sum into the same head; combine via LDS
    __syncthreads();                          // ldsA free for reuse
    float* fl = reinterpret_cast<float*>(ldsA);   // 256 floats
    if (wn == 0 && (lane & 15) == 0){
      #pragma unroll
      for (int mt = 0; mt < 4; mt++){
        #pragma unroll
        for (int r = 0; r < 4; r++){
          int rl = wm * 64 + mt * 16 + (lane >> 4) * 4 + r;
          fl[rl] = paA[mt][r]; fl[128 + rl] = pbA[mt][r];
        }
      }
    }
    __syncthreads();
    if (wn == 1 && (lane & 15) == 0){
      #pragma unroll
      for (int mt = 0; mt < 4; mt++){
        #pragma unroll
        for (int r = 0; r < 4; r++){
          int rl = wm * 64 + mt * 16 + (lane >> 4) * 4 + r;
          int row = row0 + rl;
          if (row < M){
            al[row] = fl[rl] + paA[mt][r];
            ar[row] = fl[128 + rl] + pbA[mt][r];
          }
        }
      }
    }
  }
}

// ---------------- alpha precompute: per-node softmax over incoming edges, bf16 out ----------
// one wave per node; alpha[h][i] normalized (includes 1/sum)
template<int H>
__global__ __launch_bounds__(256) void k_alpha(
    const float* __restrict__ al, const float* __restrict__ ar,
    const int* __restrict__ row_ptr, const int* __restrict__ csr_src,
    ushort* __restrict__ alpha, int N, int EN)
{
  const int tid = (int)threadIdx.x;
  const int wid = tid >> 6, lane = tid & 63;
  const int n = blockIdx.x * 4 + wid;
  if (n >= N) return;
  const int start = row_ptr[n], end = row_ptr[n + 1];
  const int deg = end - start;

  float arv[H];
  #pragma unroll
  for (int h = 0; h < H; h++) arv[h] = ar[(size_t)n * H + h];

  if (deg <= 64){
    int src = csr_src[start + (lane < deg ? lane : deg - 1)];
    float e[H];
    if constexpr (H == 4){
      float4 a4 = *reinterpret_cast<const float4*>(&al[(size_t)src * 4]);
      e[0] = a4.x + arv[0]; e[1] = a4.y + arv[1]; e[2] = a4.z + arv[2]; e[3] = a4.w + arv[3];
    } else {
      e[0] = al[src] + arv[0];
    }
    float p[H], inv[H];
    #pragma unroll
    for (int h = 0; h < H; h++){
      e[h] = e[h] > 0.f ? e[h] : 0.2f * e[h];
      if (lane >= deg) e[h] = -1e30f;
      float mx = e[h];
      #pragma unroll
      for (int off = 32; off; off >>= 1) mx = fmaxf(mx, __shfl_xor(mx, off));
      p[h] = (lane < deg) ? __expf(e[h] - mx) : 0.f;
      float s = p[h];
      #pragma unroll
      for (int off = 32; off; off >>= 1) s += __shfl_xor(s, off);
      inv[h] = 1.f / (s + 1e-16f);
    }
    if (lane < deg){
      #pragma unroll
      for (int h = 0; h < H; h++)
        alpha[(size_t)h * EN + start + lane] = f2bf(p[h] * inv[h]);
    }
  } else {
    // rare path: 3 passes
    float mx[H];
    #pragma unroll
    for (int h = 0; h < H; h++) mx[h] = -1e30f;
    for (int i = start + lane; i < end; i += 64){
      int src = csr_src[i];
      if constexpr (H == 4){
        float4 a4 = *reinterpret_cast<const float4*>(&al[(size_t)src * 4]);
        float e0 = a4.x + arv[0]; e0 = e0 > 0.f ? e0 : 0.2f * e0; mx[0] = fmaxf(mx[0], e0);
        float e1 = a4.y + arv[1]; e1 = e1 > 0.f ? e1 : 0.2f * e1; mx[1] = fmaxf(mx[1], e1);
        float e2 = a4.z + arv[2]; e2 = e2 > 0.f ? e2 : 0.2f * e2; mx[2] = fmaxf(mx[2], e2);
        float e3 = a4.w + arv[3]; e3 = e3 > 0.f ? e3 : 0.2f * e3; mx[3] = fmaxf(mx[3], e3);
      } else {
        float e = al[src] + arv[0]; e = e > 0.f ? e : 0.2f * e; mx[0] = fmaxf(mx[0], e);
      }
    }
    #pragma unroll
    for (int h = 0; h < H; h++){
      #pragma unroll
      for (int off = 32; off; off >>= 1) mx[h] = fmaxf(mx[h], __shfl_xor(mx[h], off));
    }
    float ps[H];
    #pragma unroll
    for (int h = 0; h < H; h++) ps[h] = 0.f;
    for (int i = start + lane; i < end; i += 64){
      int src = csr_src[i];
      if constexpr (H == 4){
        float4 a4 = *reinterpret_cast<const float4*>(&al[(size_t)src * 4]);
        float e0 = a4.x + arv[0]; e0 = e0 > 0.f ? e0 : 0.2f * e0; ps[0] += __expf(e0 - mx[0]);
        float e1 = a4.y + arv[1]; e1 = e1 > 0.f ? e1 : 0.2f * e1; ps[1] += __expf(e1 - mx[1]);
        float e2 = a4.z + arv[2]; e2 = e2 > 0.f ? e2 : 0.2f * e2; ps[2] += __expf(e2 - mx[2]);
        float e3 = a4.w + arv[3]; e3 = e3 > 0.f ? e3 : 0.2f * e3; ps[3] += __expf(e3 - mx[3]);
      } else {
        float e = al[src] + arv[0]; e = e > 0.f ? e : 0.2f * e; ps[0] += __expf(e - mx[0]);
      }
    }
    float inv[H];
    #pragma unroll
    for (int h = 0; h < H; h++){
      #pragma unroll
      for (int off = 32; off; off >>= 1) ps[h] += __shfl_xor(ps[h], off);
      inv[h] = 1.f / (ps[h] + 1e-16f);
    }
    for (int i = start + lane; i < end; i += 64){
      int src = csr_src[i];
      if constexpr (H == 4){
        float4 a4 = *reinterpret_cast<const float4*>(&al[(size_t)src * 4]);
        float e0 = a4.x + arv[0]; e0 = e0 > 0.f ? e0 : 0.2f * e0;
        float e1 = a4.y + arv[1]; e1 = e1 > 0.f ? e1 : 0.2f * e1;
        float e2 = a4.z + arv[2]; e2 = e2 > 0.f ? e2 : 0.2f * e2;
        float e3 = a4.w + arv[3]; e3 = e3 > 0.f ? e3 : 0.2f * e3;
        alpha[(size_t)0 * EN + i] = f2bf(__expf(e0 - mx[0]) * inv[0]);
        alpha[(size_t)1 * EN + i] = f2bf(__expf(e1 - mx[1]) * inv[1]);
        alpha[(size_t)2 * EN + i] = f2bf(__expf(e2 - mx[2]) * inv[2]);
        alpha[(size_t)3 * EN + i] = f2bf(__expf(e3 - mx[3]) * inv[3]);
      } else {
        float e = al[src] + arv[0]; e = e > 0.f ? e : 0.2f * e;
        alpha[i] = f2bf(__expf(e - mx[0]) * inv[0]);
      }
    }
  }
}

// ---------------- sliced SpMM: XCD-pinned weighted gather, bf16 pre-LN out ----------------
// grid.x = nchunk*8; slice = bid%8 -> XCD pin; per-slice working set fits 4MB XCD L2.
template<int DIM, int SC, int H>
__global__ __launch_bounds__(256) void k_spmm(
    const ushort* __restrict__ xls,     // [DIM/SC][N][SC]
    const ushort* __restrict__ alpha,   // [H][EN]
    const int* __restrict__ row_ptr, const int* __restrict__ csr_src,
    const float* __restrict__ bias,
    ushort* __restrict__ ybuf,          // [N][DIM]
    int N, int EN)
{
  constexpr int LPE = SC / 2;          // lanes per edge (uint = 2 cols each)
  constexpr int EG = 64 / LPE;         // edges per wave step
  constexpr int NPW = 8;               // nodes per wave
  const int tid = (int)threadIdx.x;
  const int wid = tid >> 6, lane = tid & 63;
  const int slice = blockIdx.x & 7;
  const int chunk = blockIdx.x >> 3;
  const int eg = lane / LPE, lc = lane % LPE;
  const int h = (slice * SC * H) / DIM;
  const ushort* xsl = xls + (size_t)slice * N * SC;
  const ushort* alp = alpha + (size_t)h * EN;
  const int colb = slice * SC + lc * 2;
  const float b0 = bias[colb], b1 = bias[colb + 1];

  const int n0 = chunk * (4 * NPW) + wid * NPW;
  for (int k = 0; k < NPW; k++){
    const int n = n0 + k;
    if (n >= N) return;
    const int start = row_ptr[n], end = row_ptr[n + 1];
    float p0 = 0.f, p1 = 0.f, q0 = 0.f, q1 = 0.f;
    int jA = start + eg, jB = start + EG + eg;
    int sA = (jA < end) ? __builtin_nontemporal_load(&csr_src[jA]) : 0;
    int sB = (jB < end) ? __builtin_nontemporal_load(&csr_src[jB]) : 0;
    float aA = (jA < end) ? bf2f(__builtin_nontemporal_load(&alp[jA])) : 0.f;
    float aB = (jB < end) ? bf2f(__builtin_nontemporal_load(&alp[jB])) : 0.f;
    for (int j = start; j < end; j += 2 * EG){
      const int jA2 = j + 2 * EG + eg, jB2 = j + 3 * EG + eg;
      int sA2 = (jA2 < end) ? __builtin_nontemporal_load(&csr_src[jA2]) : 0;
      int sB2 = (jB2 < end) ? __builtin_nontemporal_load(&csr_src[jB2]) : 0;
      float aA2 = (jA2 < end) ? bf2f(__builtin_nontemporal_load(&alp[jA2])) : 0.f;
      float aB2 = (jB2 < end) ? bf2f(__builtin_nontemporal_load(&alp[jB2])) : 0.f;
      uint vA = *reinterpret_cast<const uint*>(&xsl[(size_t)sA * SC + lc * 2]);
      uint vB = *reinterpret_cast<const uint*>(&xsl[(size_t)sB * SC + lc * 2]);
      p0 = fmaf(aA, __uint_as_float(vA << 16), p0);
      p1 = fmaf(aA, __uint_as_float(vA & 0xffff0000u), p1);
      q0 = fmaf(aB, __uint_as_float(vB << 16), q0);
      q1 = fmaf(aB, __uint_as_float(vB & 0xffff0000u), q1);
      sA = sA2; sB = sB2; aA = aA2; aB = aB2;
    }
    float a0 = p0 + q0, a1 = p1 + q1;
    #pragma unroll
    for (int off = LPE; off < 64; off <<= 1){ a0 += __shfl_xor(a0, off); a1 += __shfl_xor(a1, off); }
    if (lane < LPE){
      uint pk = (uint)f2bf(a0 + b0) | ((uint)f2bf(a1 + b1) << 16);
      __builtin_nontemporal_store(pk, reinterpret_cast<uint*>(&ybuf[(size_t)n * DIM + colb]));
    }
  }
}

// ---------------- LayerNorm + ReLU over ybuf rows ----------------
template<int DIM, bool F32OUT>
__global__ __launch_bounds__(256) void k_ln(const ushort* __restrict__ ybuf,
    const float* __restrict__ gamma, const float* __restrict__ beta,
    void* __restrict__ outp, int N)
{
  constexpr int EPL = DIM / 64;        // 4 or 2
  const int tid = (int)threadIdx.x;
  const int wid = tid >> 6, lane = tid & 63;
  const int n = blockIdx.x * 4 + wid;
  if (n >= N) return;
  float v[EPL];
  if constexpr (EPL == 4){
    uint2 pv = *reinterpret_cast<const uint2*>(&ybuf[(size_t)n * DIM + lane * 4]);
    v[0] = __uint_as_float(pv.x << 16); v[1] = __uint_as_float(pv.x & 0xffff0000u);
    v[2] = __uint_as_float(pv.y << 16); v[3] = __uint_as_float(pv.y & 0xffff0000u);
  } else {
    uint pv = *reinterpret_cast<const uint*>(&ybuf[(size_t)n * DIM + lane * 2]);
    v[0] = __uint_as_float(pv << 16); v[1] = __uint_as_float(pv & 0xffff0000u);
  }
  float s1 = 0.f, s2 = 0.f;
  #pragma unroll
  for (int e = 0; e < EPL; e++){ s1 += v[e]; s2 += v[e] * v[e]; }
  #pragma unroll
  for (int off = 32; off; off >>= 1){ s1 += __shfl_xor(s1, off); s2 += __shfl_xor(s2, off); }
  const float mu = s1 / DIM;
  const float rstd = rsqrtf(s2 / DIM - mu * mu + EPS_LN);

  if constexpr (EPL == 4){
    float4 gg = *reinterpret_cast<const float4*>(&gamma[lane * 4]);
    float4 be = *reinterpret_cast<const float4*>(&beta[lane * 4]);
    float o0 = fmaxf((v[0] - mu) * rstd * gg.x + be.x, 0.f);
    float o1 = fmaxf((v[1] - mu) * rstd * gg.y + be.y, 0.f);
    float o2 = fmaxf((v[2] - mu) * rstd * gg.z + be.z, 0.f);
    float o3 = fmaxf((v[3] - mu) * rstd * gg.w + be.w, 0.f);
    uint2 pk;
    pk.x = (uint)f2bf(o0) | ((uint)f2bf(o1) << 16);
    pk.y = (uint)f2bf(o2) | ((uint)f2bf(o3) << 16);
    *reinterpret_cast<uint2*>(&reinterpret_cast<ushort*>(outp)[(size_t)n * DIM + lane * 4]) = pk;
  } else {
    float2 gg = *reinterpret_cast<const float2*>(&gamma[lane * 2]);
    float2 be = *reinterpret_cast<const float2*>(&beta[lane * 2]);
    float o0 = fmaxf((v[0] - mu) * rstd * gg.x + be.x, 0.f);
    float o1 = fmaxf((v[1] - mu) * rstd * gg.y + be.y, 0.f);
    if constexpr (F32OUT){
      *reinterpret_cast<float2*>(&reinterpret_cast<float*>(outp)[(size_t)n * DIM + lane * 2]) = make_float2(o0, o1);
    } else {
      uint pk = (uint)f2bf(o0) | ((uint)f2bf(o1) << 16);
      *reinterpret_cast<uint*>(&reinterpret_cast<ushort*>(outp)[(size_t)n * DIM + lane * 2]) = pk;
    }
  }
}

// ---------------- pooling over pos ranges ----------------
__global__ __launch_bounds__(128) void k_pool(const float* __restrict__ h, const int* __restrict__ pos,
    float* __restrict__ pool_sum, unsigned* __restrict__ pool_max){
  const int c = (int)threadIdx.x;           // channel 0..127
  const int g = blockIdx.x >> 2;            // graph
  const int q = blockIdx.x & 3;             // quarter
  const int s = pos[g], e = pos[g + 1];
  const int len = e - s;
  if (len <= 0) return;
  const int chunk = (len + 3) >> 2;
  const int n0 = s + q * chunk;
  const int n1 = min(n0 + chunk, e);
  if (n0 >= n1) return;
  float sum = 0.f, mx = 0.f;                // post-ReLU values >= 0
  for (int n = n0; n < n1; n++){
    float v = h[(size_t)n * 128 + c];
    sum += v; mx = fmaxf(mx, v);
  }
  atomicAdd(&pool_sum[g * 128 + c], sum);
  atomicMax(&pool_max[g * 128 + c], __float_as_uint(mx));
}

__global__ __launch_bounds__(128) void k_final(const float* __restrict__ pool_sum,
    const unsigned* __restrict__ pool_max, const int* __restrict__ pos,
    const float* __restrict__ Wp, const float* __restrict__ bp, float* __restrict__ out){
  const int g = blockIdx.x;
  const int j = (int)threadIdx.x;
  float inv = 1.f / fmaxf((float)(pos[g + 1] - pos[g]), 1.f);
  float acc = bp[j];
  #pragma unroll 4
  for (int k = 0; k < 128; k++)
    acc = fmaf(pool_sum[g * 128 + k] * inv, Wp[k * 128 + j], acc);
  #pragma unroll 4
  for (int k = 0; k < 128; k++)
    acc = fmaf(__uint_as_float(pool_max[g * 128 + k]), Wp[(128 + k) * 128 + j], acc);
  out[g * 128 + j] = acc;
}

// ---------------- launch ----------------
extern "C" void kernel_launch(void* const* d_in, const int* in_sizes, int n_in,
                              void* d_out, int out_size, void* d_ws, size_t ws_size,
                              hipStream_t stream){
  const float* x     = (const float*)d_in[0];
  const int*   ei    = (const int*)d_in[1];
  const int*   batch = (const int*)d_in[2];
  const float* W1    = (const float*)d_in[3];
  const float* asrc1 = (const float*)d_in[4];
  const float* adst1 = (const float*)d_in[5];
  const float* b1    = (const float*)d_in[6];
  const float* g1    = (const float*)d_in[7];
  const float* be1   = (const float*)d_in[8];
  const float* W2    = (const float*)d_in[9];
  const float* asrc2 = (const float*)d_in[10];
  const float* adst2 = (const float*)d_in[11];
  const float* b2    = (const float*)d_in[12];
  const float* g2    = (const float*)d_in[13];
  const float* be2   = (const float*)d_in[14];
  const float* W3    = (const float*)d_in[15];
  const float* asrc3 = (const float*)d_in[16];
  const float* adst3 = (const float*)d_in[17];
  const float* b3    = (const float*)d_in[18];
  const float* g3    = (const float*)d_in[19];
  const float* be3   = (const float*)d_in[20];
  const float* Wp    = (const float*)d_in[21];
  const float* bp    = (const float*)d_in[22];

  const int N = in_sizes[0] / 128;
  const int E = in_sizes[1] / 2;
  const int G = out_size / 128;
  const int EN = E + N;

  char* ws = (char*)d_ws;
  size_t off = 0;
  auto alloc = [&](size_t bytes) -> char* {
    char* p = ws + off;
    off = (off + bytes + 255) & ~(size_t)255;
    return p;
  };
  // region0: x_bf (N*128 bf16) lives here until k_ln L1 overwrites it with h_bf (N*256 bf16)
  ushort*   region0  = (ushort*)alloc((size_t)N * 256 * 2);
  ushort*   x_bf     = region0;
  ushort*   h_bf     = region0;
  ushort*   xls      = (ushort*)alloc((size_t)N * 256 * 2);  // sliced xl (bf16)
  ushort*   ybuf     = (ushort*)alloc((size_t)N * 256 * 2);  // pre-LN biased agg (bf16)
  ushort*   alphaB   = (ushort*)alloc((size_t)4 * EN * 2);   // alpha [H][EN] bf16
  float*    xbufB    = (float*)alloc((size_t)N * 128 * 4);   // layer-3 output (f32, pooling)
  float*    al       = (float*)alloc((size_t)N * 4 * 4);
  float*    ar       = (float*)alloc((size_t)N * 4 * 4);
  int*      deg      = (int*)alloc((size_t)N * 4);
  int*      row_ptr  = (int*)alloc((size_t)(N + 1) * 4);
  int*      cursor   = (int*)alloc((size_t)N * 4);
  int*      csr_src  = (int*)alloc((size_t)EN * 4);
  int*      pos      = (int*)alloc((size_t)(G + 1) * 4);
  float*    pool_sum = (float*)alloc((size_t)G * 128 * 4);
  unsigned* pool_max = (unsigned*)alloc((size_t)G * 128 * 4);
  ushort*   W1t      = (ushort*)alloc((size_t)256 * 128 * 2);  // [N=256][K=128]
  ushort*   W2t      = (ushort*)alloc((size_t)256 * 256 * 2);  // [256][256]
  ushort*   W3t      = (ushort*)alloc((size_t)128 * 256 * 2);  // [128][256]
  const int NB = (N + 1023) / 1024;
  int*      bsum     = (int*)alloc((size_t)NB * 4);

  hipMemsetAsync(deg, 0, (size_t)N * 4, stream);
  hipMemsetAsync(pool_sum, 0, (size_t)G * 128 * 4, stream);
  hipMemsetAsync(pool_max, 0, (size_t)G * 128 * 4, stream);

  // CSR build + graph bounds + dtype prep
  k_deg<<<(EN + 255) / 256, 256, 0, stream>>>(ei, deg, E, N);
  k_bsum<<<NB, 1024, 0, stream>>>(deg, bsum, N);
  k_misc<<<2, 256, 0, stream>>>(bsum, NB, batch, pos, N, G);
  k_scan2<<<NB, 1024, 0, stream>>>(deg, bsum, row_ptr, cursor, N);
  k_scatter<<<(EN + 255) / 256, 256, 0, stream>>>(ei, cursor, csr_src, E, N);
  {
    int total = N * 32 + 256 * 128 + 256 * 256 + 128 * 256;
    k_prep<<<(total + 255) / 256, 256, 0, stream>>>(x, x_bf, W1, W1t, W2, W2t, W3, W3t, N);
  }

  const int MB = (N + 127) / 128;
  const int NB4 = (N + 3) / 4;
  const int NCH = ((N + 31) / 32) * 8;   // spmm grid: nchunk x 8 slices (XCD-pinned)

  // Layer 1: 128 -> 256, H=4
  k_mm<128, 256, 4, 32><<<dim3(MB, 2), 256, 0, stream>>>(x_bf, W1t, xls, asrc1, adst1, al, ar, N);
  k_alpha<4><<<NB4, 256, 0, stream>>>(al, ar, row_ptr, csr_src, alphaB, N, EN);
  k_spmm<256, 32, 4><<<NCH, 256, 0, stream>>>(xls, alphaB, row_ptr, csr_src, b1, ybuf, N, EN);
  k_ln<256, false><<<NB4, 256, 0, stream>>>(ybuf, g1, be1, h_bf, N);

  // Layer 2: 256 -> 256, H=4
  k_mm<256, 256, 4, 32><<<dim3(MB, 2), 256, 0, stream>>>(h_bf, W2t, xls, asrc2, adst2, al, ar, N);
  k_alpha<4><<<NB4, 256, 0, stream>>>(al, ar, row_ptr, csr_src, alphaB, N, EN);
  k_spmm<256, 32, 4><<<NCH, 256, 0, stream>>>(xls, alphaB, row_ptr, csr_src, b2, ybuf, N, EN);
  k_ln<256, false><<<NB4, 256, 0, stream>>>(ybuf, g2, be2, h_bf, N);

  // Layer 3: 256 -> 128, H=1
  k_mm<256, 128, 1, 16><<<dim3(MB, 1), 256, 0, stream>>>(h_bf, W3t, xls, asrc3, adst3, al, ar, N);
  k_alpha<1><<<NB4, 256, 0, stream>>>(al, ar, row_ptr, csr_src, alphaB, N, EN);
  k_spmm<128, 16, 1><<<NCH, 256, 0, stream>>>(xls, alphaB, row_ptr, csr_src, b3, ybuf, N, EN);
  k_ln<128, true><<<NB4, 256, 0, stream>>>(ybuf, g3, be3, xbufB, N);

  // Pooling + final projection
  k_pool<<<G * 4, 128, 0, stream>>>(xbufB, pos, pool_sum, pool_max);
  k_final<<<G, 128, 0, stream>>>(pool_sum, pool_max, pos, Wp, bp, (float*)d_out);
}

// Round 10
// 508.781 us; speedup vs baseline: 1.9309x; 1.9309x over previous
//
#include <hip/hip_runtime.h>

#define EPS_LN 1e-5f
typedef unsigned int uint;

using bf16x8 = __attribute__((ext_vector_type(8))) short;
using f32x4  = __attribute__((ext_vector_type(4))) float;

__device__ inline float bf2f(ushort h){ return __uint_as_float(((uint)h) << 16); }
__device__ inline ushort f2bf(float f){
  uint u = __float_as_uint(f);
  u += 0x7fffu + ((u >> 16) & 1u);   // round-to-nearest-even
  return (ushort)(u >> 16);
}

// ---------------- mega-prep: cast x, transpose/cast W1-3, deg histogram, bounds, zeroing ----
__global__ void k_prep(const float* __restrict__ x, ushort* __restrict__ x_bf,
                       const float* __restrict__ W1, ushort* __restrict__ W1t,
                       const float* __restrict__ W2, ushort* __restrict__ W2t,
                       const float* __restrict__ W3, ushort* __restrict__ W3t,
                       const int* __restrict__ ei, int* __restrict__ deg,
                       const int* __restrict__ batch, int* __restrict__ pos,
                       float* __restrict__ pool_sum, uint* __restrict__ pool_max,
                       int* __restrict__ done, int* __restrict__ flag,
                       int N, int E, int G, int NB){
  int i = blockIdx.x * 256 + threadIdx.x;
  const int c0 = N * 32;                    // float4 quads of x
  if (i < c0){
    float4 v = reinterpret_cast<const float4*>(x)[i];
    ushort4 o; o.x = f2bf(v.x); o.y = f2bf(v.y); o.z = f2bf(v.z); o.w = f2bf(v.w);
    reinterpret_cast<ushort4*>(x_bf)[i] = o;
    return;
  }
  i -= c0;
  if (i < 256 * 128){                       // W1t[n*128+k] = W1[k*256+n]
    int n = i >> 7, k = i & 127;
    W1t[i] = f2bf(W1[(size_t)k * 256 + n]);
    return;
  }
  i -= 256 * 128;
  if (i < 256 * 256){                       // W2t[n*256+k] = W2[k*256+n]
    int n = i >> 8, k = i & 255;
    W2t[i] = f2bf(W2[(size_t)k * 256 + n]);
    return;
  }
  i -= 256 * 256;
  if (i < 128 * 256){                       // W3t[n*256+k] = W3[k*128+n]
    int n = i >> 8, k = i & 255;
    W3t[i] = f2bf(W3[(size_t)k * 128 + n]);
    return;
  }
  i -= 128 * 256;
  if (i < E + N){                           // degree histogram (deg pre-zeroed by memset)
    int dst = (i < E) ? ei[E + i] : (i - E);
    atomicAdd(&deg[dst], 1);
    return;
  }
  i -= E + N;
  if (i < G * 128){                         // zero pooling buffers + misc small inits
    pool_sum[i] = 0.f;
    pool_max[i] = 0u;
    if (i < G) done[i] = 0;
    if (i < NB) flag[i] = 0;
    if (i <= G){                            // graph bounds: first idx with batch[idx] >= i
      int lo = 0, hi = N;
      while (lo < hi){
        int mid = (lo + hi) >> 1;
        if (batch[mid] < i) lo = mid + 1; else hi = mid;
      }
      pos[i] = lo;
    }
  }
}

// ---------------- single-pass decoupled-lookback scan: deg -> row_ptr, cursor --------------
__global__ __launch_bounds__(1024) void k_scanall(const int* __restrict__ deg,
    int* __restrict__ row_ptr, int* __restrict__ cursor,
    int* __restrict__ pref, int* __restrict__ flag, int n){
  __shared__ int wsum[16];
  __shared__ int prev_s;
  const int b = (int)blockIdx.x;
  const int t = (int)threadIdx.x, lane = t & 63, w = t >> 6;
  int i = b * 1024 + t;
  int v = (i < n) ? deg[i] : 0;
  int s = v;
  #pragma unroll
  for (int off = 1; off < 64; off <<= 1){ int u = __shfl_up(s, off); if (lane >= off) s += u; }
  if (lane == 63) wsum[w] = s;
  __syncthreads();
  if (w == 0 && lane < 16){
    int sc = wsum[lane];
    #pragma unroll
    for (int off = 1; off < 16; off <<= 1){ int u = __shfl_up(sc, off); if (lane >= off) sc += u; }
    wsum[lane] = sc;
  }
  __syncthreads();
  const int local_inc = (w ? wsum[w - 1] : 0) + s;      // inclusive within block
  // lookback chain (49 blocks, all co-resident)
  if (t == 0){
    int prev = 0;
    if (b > 0){
      while (atomicCAS(&flag[b - 1], 1, 1) == 0){}
      __threadfence();
      prev = pref[b - 1];
    }
    pref[b] = prev + wsum[15];
    __threadfence();
    atomicExch(&flag[b], 1);
    prev_s = prev;
  }
  __syncthreads();
  const int prefix = prev_s + local_inc;
  if (i < n){ row_ptr[i + 1] = prefix; cursor[i] = prefix - v; }
  if (i == 0) row_ptr[0] = 0;
}

__global__ void k_scatter(const int* __restrict__ ei, int* __restrict__ cursor,
                          int* __restrict__ csr_src, int E, int N){
  int e = blockIdx.x * 256 + threadIdx.x;
  if (e >= E + N) return;
  int src, dst;
  if (e < E){ src = ei[e]; dst = ei[E + e]; } else { src = dst = e - E; }
  int pos = atomicAdd(&cursor[dst], 1);
  csr_src[pos] = src;
}

// ---------------- MFMA GEMM + fused attention-coef epilogue ----------------
// out[M,N](bf16) = A[M,K](bf16) @ Wt[N,K](bf16)^T ; al/ar[row,h] = sum_c acc[row,c]*asrc/adst[c]
template<int K, int N, int H>
__global__ __launch_bounds__(256, 2) void k_mm(const ushort* __restrict__ A,
                                               const ushort* __restrict__ Wt,
                                               ushort* __restrict__ out,
                                               const float* __restrict__ asrc,
                                               const float* __restrict__ adst,
                                               float* __restrict__ al, float* __restrict__ ar,
                                               int M)
{
  constexpr int BANDS = (N / H) / 64;   // 64-col bands per head: 1 (H=4,N=256) or 2 (H=1,N=128)
  __shared__ __align__(16) ushort ldsA[128 * 128];
  __shared__ __align__(16) ushort ldsB[128 * 128];

  const int t = (int)threadIdx.x;
  const int lane = t & 63;
  const int w = t >> 6;
  const int wm = w >> 1, wn = w & 1;
  const int row0 = blockIdx.x * 128;
  const int n0 = blockIdx.y * 128;
  const int trow = t >> 4;     // 0..15
  const int tk = t & 15;       // kb8 index

  f32x4 acc[4][4];
  #pragma unroll
  for (int mt = 0; mt < 4; mt++)
    #pragma unroll
    for (int nt = 0; nt < 4; nt++)
      acc[mt][nt] = (f32x4){0.f, 0.f, 0.f, 0.f};

  #pragma unroll
  for (int kt = 0; kt < K / 128; kt++){
    uint4 ra[8], rb[8];
    #pragma unroll
    for (int p = 0; p < 8; p++){
      int arow = p * 16 + trow;
      int grow = row0 + arow; if (grow > M - 1) grow = M - 1;
      ra[p] = *reinterpret_cast<const uint4*>(&A[(size_t)grow * K + kt * 128 + tk * 8]);
      rb[p] = *reinterpret_cast<const uint4*>(&Wt[(size_t)(n0 + arow) * K + kt * 128 + tk * 8]);
    }
    if (kt) __syncthreads();          // previous tile fully consumed
    #pragma unroll
    for (int p = 0; p < 8; p++){
      int arow = p * 16 + trow;
      int sw = (tk ^ (arow & 7)) * 8;
      *reinterpret_cast<uint4*>(&ldsA[arow * 128 + sw]) = ra[p];
      *reinterpret_cast<uint4*>(&ldsB[arow * 128 + sw]) = rb[p];
    }
    __syncthreads();

    #pragma unroll
    for (int ks = 0; ks < 4; ks++){
      bf16x8 af[4], bfr[4];
      const int kb8 = ks * 4 + (lane >> 4);
      #pragma unroll
      for (int mt = 0; mt < 4; mt++){
        int arow = wm * 64 + mt * 16 + (lane & 15);
        af[mt] = *reinterpret_cast<const bf16x8*>(&ldsA[arow * 128 + ((kb8 ^ (arow & 7)) * 8)]);
        int brow = wn * 64 + mt * 16 + (lane & 15);
        bfr[mt] = *reinterpret_cast<const bf16x8*>(&ldsB[brow * 128 + ((kb8 ^ (brow & 7)) * 8)]);
      }
      #pragma unroll
      for (int mt = 0; mt < 4; mt++)
        #pragma unroll
        for (int nt = 0; nt < 4; nt++)
          acc[mt][nt] = __builtin_amdgcn_mfma_f32_16x16x32_bf16(af[mt], bfr[nt], acc[mt][nt], 0, 0, 0);
    }
  }

  // ---- epilogue 1: C store (C/D map col=lane&15, row=(lane>>4)*4+r, m89-verified) ----
  #pragma unroll
  for (int mt = 0; mt < 4; mt++){
    const int grow_b = row0 + wm * 64 + mt * 16 + (lane >> 4) * 4;
    #pragma unroll
    for (int nt = 0; nt < 4; nt++){
      const int gcol = n0 + wn * 64 + nt * 16 + (lane & 15);
      #pragma unroll
      for (int r = 0; r < 4; r++){
        int grow = grow_b + r;
        if (grow < M) out[(size_t)grow * N + gcol] = f2bf(acc[mt][nt][r]);
      }
    }
  }

  // ---- epilogue 2: fused attention coefficients from f32 accumulators ----
  float av[4], bv[4];
  #pragma unroll
  for (int nt = 0; nt < 4; nt++){
    int col = n0 + wn * 64 + nt * 16 + (lane & 15);
    av[nt] = asrc[col]; bv[nt] = adst[col];
  }
  float paA[4][4], pbA[4][4];     // [mt][r], reduced over the 64-col band
  #pragma unroll
  for (int mt = 0; mt < 4; mt++){
    #pragma unroll
    for (int r = 0; r < 4; r++){
      float pa = acc[mt][0][r] * av[0] + acc[mt][1][r] * av[1]
               + acc[mt][2][r] * av[2] + acc[mt][3][r] * av[3];
      float pb = acc[mt][0][r] * bv[0] + acc[mt][1][r] * bv[1]
               + acc[mt][2][r] * bv[2] + acc[mt][3][r] * bv[3];
      #pragma unroll
      for (int off = 1; off < 16; off <<= 1){ pa += __shfl_xor(pa, off); pb += __shfl_xor(pb, off); }
      paA[mt][r] = pa; pbA[mt][r] = pb;
    }
  }
  if constexpr (BANDS == 1){
    // each (row, head) produced by exactly one wave: plain store
    const int h = (n0 + wn * 64) / (N / H);
    if ((lane & 15) == 0){
      #pragma unroll
      for (int mt = 0; mt < 4; mt++){
        #pragma unroll
        for (int r = 0; r < 4; r++){
          int row = row0 + wm * 64 + mt * 16 + (lane >> 4) * 4 + r;
          if (row < M){
            al[(size_t)row * H + h] = paA[mt][r];
            ar[(size_t)row * H + h] = pbA[mt][r];
          }
        }
      }
    }
  } else {
    // H=1: two column bands (wn=0,1) sum into the same head; combine via LDS
    __syncthreads();                          // ldsA free for reuse
    float* fl = reinterpret_cast<float*>(ldsA);   // 256 floats
    if (wn == 0 && (lane & 15) == 0){
      #pragma unroll
      for (int mt = 0; mt < 4; mt++){
        #pragma unroll
        for (int r = 0; r < 4; r++){
          int rl = wm * 64 + mt * 16 + (lane >> 4) * 4 + r;
          fl[rl] = paA[mt][r]; fl[128 + rl] = pbA[mt][r];
        }
      }
    }
    __syncthreads();
    if (wn == 1 && (lane & 15) == 0){
      #pragma unroll
      for (int mt = 0; mt < 4; mt++){
        #pragma unroll
        for (int r = 0; r < 4; r++){
          int rl = wm * 64 + mt * 16 + (lane >> 4) * 4 + r;
          int row = row0 + rl;
          if (row < M){
            al[row] = fl[rl] + paA[mt][r];
            ar[row] = fl[128 + rl] + pbA[mt][r];
          }
        }
      }
    }
  }
}

// ---- gather helpers: one edge row contribution ----
template<int DIM>
__device__ inline void gstep4(const char* __restrict__ xlb, int laneB, int s, float p, float* acc){
  uint2 v = *reinterpret_cast<const uint2*>(xlb + (size_t)((uint)s * (uint)(DIM * 2)) + laneB);
  acc[0] = fmaf(p, __uint_as_float(v.x << 16), acc[0]);
  acc[1] = fmaf(p, __uint_as_float(v.x & 0xffff0000u), acc[1]);
  acc[2] = fmaf(p, __uint_as_float(v.y << 16), acc[2]);
  acc[3] = fmaf(p, __uint_as_float(v.y & 0xffff0000u), acc[3]);
}
template<int DIM>
__device__ inline void gstep2(const char* __restrict__ xlb, int laneB, int s, float p, float* acc){
  uint v = *reinterpret_cast<const uint*>(xlb + (size_t)((uint)s * (uint)(DIM * 2)) + laneB);
  acc[0] = fmaf(p, __uint_as_float(v << 16), acc[0]);
  acc[1] = fmaf(p, __uint_as_float(v & 0xffff0000u), acc[1]);
}

// ---------------- per-node wave gather: softmax + aggregate + bias + LN + ReLU ----------------
// One WAVE per node (4 waves/block, independent). src+p cached in LDS; no global re-reads in j-loop.
template<int H, int DIM, bool BF16_OUT>
__global__ __launch_bounds__(256) void k_aggw(
    const ushort* __restrict__ xl,
    const float* __restrict__ al, const float* __restrict__ ar,
    const int* __restrict__ row_ptr, const int* __restrict__ csr_src,
    const float* __restrict__ bias, const float* __restrict__ gamma, const float* __restrict__ beta,
    float* __restrict__ out, int N)
{
  constexpr int EPL = DIM / 64;        // cols per lane: 4 (DIM=256) or 2 (DIM=128)
  constexpr int PST = 68;              // padded p stride: conflict-free broadcast
  const int tid = (int)threadIdx.x;
  const int wid = tid >> 6, lane = tid & 63;
  __shared__ float plds_all[4][H * PST];
  __shared__ int   slds_all[4][64];
  float* plds = plds_all[wid];
  int*   slds = slds_all[wid];
  const int n = blockIdx.x * 4 + wid;
  if (n >= N) return;
  const int start = __builtin_amdgcn_readfirstlane(row_ptr[n]);
  const int end   = __builtin_amdgcn_readfirstlane(row_ptr[n + 1]);
  const int deg   = end - start;
  const int hm    = (H == 4) ? (lane >> 4) : 0;
  const int hb    = hm * PST;
  const int laneB = lane * (EPL * 2);

  float arv[H];
  #pragma unroll
  for (int h = 0; h < H; h++) arv[h] = ar[(size_t)n * H + h];

  float acc[EPL];
  #pragma unroll
  for (int e = 0; e < EPL; e++) acc[e] = 0.f;
  float psum[H];
  const char* xlb = (const char*)xl;

  auto gather = [&](int cnt){
    int j = 0;
    for (; j + 8 <= cnt; j += 8){
      int s0 = slds[j+0], s1 = slds[j+1], s2 = slds[j+2], s3 = slds[j+3];
      int s4 = slds[j+4], s5 = slds[j+5], s6 = slds[j+6], s7 = slds[j+7];
      float q0 = plds[hb+j+0], q1 = plds[hb+j+1], q2 = plds[hb+j+2], q3 = plds[hb+j+3];
      float q4 = plds[hb+j+4], q5 = plds[hb+j+5], q6 = plds[hb+j+6], q7 = plds[hb+j+7];
      if constexpr (EPL == 4){
        gstep4<DIM>(xlb, laneB, s0, q0, acc); gstep4<DIM>(xlb, laneB, s1, q1, acc);
        gstep4<DIM>(xlb, laneB, s2, q2, acc); gstep4<DIM>(xlb, laneB, s3, q3, acc);
        gstep4<DIM>(xlb, laneB, s4, q4, acc); gstep4<DIM>(xlb, laneB, s5, q5, acc);
        gstep4<DIM>(xlb, laneB, s6, q6, acc); gstep4<DIM>(xlb, laneB, s7, q7, acc);
      } else {
        gstep2<DIM>(xlb, laneB, s0, q0, acc); gstep2<DIM>(xlb, laneB, s1, q1, acc);
        gstep2<DIM>(xlb, laneB, s2, q2, acc); gstep2<DIM>(xlb, laneB, s3, q3, acc);
        gstep2<DIM>(xlb, laneB, s4, q4, acc); gstep2<DIM>(xlb, laneB, s5, q5, acc);
        gstep2<DIM>(xlb, laneB, s6, q6, acc); gstep2<DIM>(xlb, laneB, s7, q7, acc);
      }
    }
    for (; j + 2 <= cnt; j += 2){
      int s0 = slds[j+0], s1 = slds[j+1];
      float q0 = plds[hb+j+0], q1 = plds[hb+j+1];
      if constexpr (EPL == 4){ gstep4<DIM>(xlb, laneB, s0, q0, acc); gstep4<DIM>(xlb, laneB, s1, q1, acc); }
      else                   { gstep2<DIM>(xlb, laneB, s0, q0, acc); gstep2<DIM>(xlb, laneB, s1, q1, acc); }
    }
    if (j < cnt){
      int s0 = slds[j];
      float q0 = plds[hb+j];
      if constexpr (EPL == 4) gstep4<DIM>(xlb, laneB, s0, q0, acc);
      else                    gstep2<DIM>(xlb, laneB, s0, q0, acc);
    }
  };

  if (deg <= 64){
    // ---- fast path: one al gather; e/p in registers; src cached to LDS ----
    int src = csr_src[start + (lane < deg ? lane : deg - 1)];
    slds[lane] = src;
    float e[H];
    if constexpr (H == 4){
      float4 a4 = *reinterpret_cast<const float4*>(&al[(size_t)src * 4]);
      e[0] = a4.x + arv[0]; e[1] = a4.y + arv[1]; e[2] = a4.z + arv[2]; e[3] = a4.w + arv[3];
    } else {
      e[0] = al[src] + arv[0];
    }
    #pragma unroll
    for (int h = 0; h < H; h++){
      e[h] = e[h] > 0.f ? e[h] : 0.2f * e[h];
      if (lane >= deg) e[h] = -1e30f;
    }
    float mx[H];
    #pragma unroll
    for (int h = 0; h < H; h++){
      mx[h] = e[h];
      #pragma unroll
      for (int off = 32; off; off >>= 1) mx[h] = fmaxf(mx[h], __shfl_xor(mx[h], off));
    }
    #pragma unroll
    for (int h = 0; h < H; h++){
      float p = (lane < deg) ? __expf(e[h] - mx[h]) : 0.f;
      plds[h * PST + lane] = p;
      psum[h] = p;
      #pragma unroll
      for (int off = 32; off; off >>= 1) psum[h] += __shfl_xor(psum[h], off);
    }
    __asm__ volatile("s_waitcnt lgkmcnt(0)" ::: "memory");
    __builtin_amdgcn_wave_barrier();
    gather(deg);
  } else {
    // ---- slow path (deg > 64, rare): global max pass then chunked ----
    float mx[H];
    #pragma unroll
    for (int h = 0; h < H; h++) mx[h] = -1e30f;
    for (int i = start + lane; i < end; i += 64){
      int src = csr_src[i];
      if constexpr (H == 4){
        float4 a4 = *reinterpret_cast<const float4*>(&al[(size_t)src * 4]);
        float e0 = a4.x + arv[0]; e0 = e0 > 0.f ? e0 : 0.2f * e0; mx[0] = fmaxf(mx[0], e0);
        float e1 = a4.y + arv[1]; e1 = e1 > 0.f ? e1 : 0.2f * e1; mx[1] = fmaxf(mx[1], e1);
        float e2 = a4.z + arv[2]; e2 = e2 > 0.f ? e2 : 0.2f * e2; mx[2] = fmaxf(mx[2], e2);
        float e3 = a4.w + arv[3]; e3 = e3 > 0.f ? e3 : 0.2f * e3; mx[3] = fmaxf(mx[3], e3);
      } else {
        float e = al[src] + arv[0]; e = e > 0.f ? e : 0.2f * e; mx[0] = fmaxf(mx[0], e);
      }
    }
    #pragma unroll
    for (int h = 0; h < H; h++){
      #pragma unroll
      for (int off = 32; off; off >>= 1) mx[h] = fmaxf(mx[h], __shfl_xor(mx[h], off));
    }
    #pragma unroll
    for (int h = 0; h < H; h++) psum[h] = 0.f;
    for (int c0 = start; c0 < end; c0 += 64){
      const int cnt = min(64, end - c0);
      __asm__ volatile("s_waitcnt lgkmcnt(0)" ::: "memory");   // prev chunk consumed
      __builtin_amdgcn_wave_barrier();
      if (lane < cnt){
        int src = csr_src[c0 + lane];
        slds[lane] = src;
        if constexpr (H == 4){
          float4 a4 = *reinterpret_cast<const float4*>(&al[(size_t)src * 4]);
          float e0 = a4.x + arv[0]; e0 = e0 > 0.f ? e0 : 0.2f * e0; float p0 = __expf(e0 - mx[0]);
          float e1 = a4.y + arv[1]; e1 = e1 > 0.f ? e1 : 0.2f * e1; float p1 = __expf(e1 - mx[1]);
          float e2 = a4.z + arv[2]; e2 = e2 > 0.f ? e2 : 0.2f * e2; float p2 = __expf(e2 - mx[2]);
          float e3 = a4.w + arv[3]; e3 = e3 > 0.f ? e3 : 0.2f * e3; float p3 = __expf(e3 - mx[3]);
          plds[0 * PST + lane] = p0; plds[1 * PST + lane] = p1;
          plds[2 * PST + lane] = p2; plds[3 * PST + lane] = p3;
          psum[0] += p0; psum[1] += p1; psum[2] += p2; psum[3] += p3;
        } else {
          float e = al[src] + arv[0]; e = e > 0.f ? e : 0.2f * e; float p = __expf(e - mx[0]);
          plds[lane] = p; psum[0] += p;
        }
      }
      __asm__ volatile("s_waitcnt lgkmcnt(0)" ::: "memory");
      __builtin_amdgcn_wave_barrier();
      gather(cnt);
    }
    #pragma unroll
    for (int h = 0; h < H; h++){
      #pragma unroll
      for (int off = 32; off; off >>= 1) psum[h] += __shfl_xor(psum[h], off);
    }
  }

  // ---- normalize ----
  float ssel;
  if constexpr (H == 4){
    ssel = (hm == 0) ? psum[0] : (hm == 1) ? psum[1] : (hm == 2) ? psum[2] : psum[3];
  } else {
    ssel = psum[0];
  }
  const float inv = 1.f / (ssel + 1e-16f);

  // ---- bias + LayerNorm + ReLU (all-shuffle, no LDS) ----
  float v[EPL];
  if constexpr (EPL == 4){
    float4 bb = *reinterpret_cast<const float4*>(&bias[lane * 4]);
    v[0] = fmaf(acc[0], inv, bb.x); v[1] = fmaf(acc[1], inv, bb.y);
    v[2] = fmaf(acc[2], inv, bb.z); v[3] = fmaf(acc[3], inv, bb.w);
  } else {
    float2 bb = *reinterpret_cast<const float2*>(&bias[lane * 2]);
    v[0] = fmaf(acc[0], inv, bb.x); v[1] = fmaf(acc[1], inv, bb.y);
  }
  float s1 = 0.f, s2 = 0.f;
  #pragma unroll
  for (int e = 0; e < EPL; e++){ s1 += v[e]; s2 += v[e] * v[e]; }
  #pragma unroll
  for (int off = 32; off; off >>= 1){ s1 += __shfl_xor(s1, off); s2 += __shfl_xor(s2, off); }
  const float mu = s1 / DIM;
  const float rstd = rsqrtf(s2 / DIM - mu * mu + EPS_LN);

  if constexpr (EPL == 4){
    float4 gg = *reinterpret_cast<const float4*>(&gamma[lane * 4]);
    float4 be = *reinterpret_cast<const float4*>(&beta[lane * 4]);
    float o0 = fmaxf((v[0] - mu) * rstd * gg.x + be.x, 0.f);
    float o1 = fmaxf((v[1] - mu) * rstd * gg.y + be.y, 0.f);
    float o2 = fmaxf((v[2] - mu) * rstd * gg.z + be.z, 0.f);
    float o3 = fmaxf((v[3] - mu) * rstd * gg.w + be.w, 0.f);
    if constexpr (BF16_OUT){
      uint2 pk;
      pk.x = (uint)f2bf(o0) | ((uint)f2bf(o1) << 16);
      pk.y = (uint)f2bf(o2) | ((uint)f2bf(o3) << 16);
      *reinterpret_cast<uint2*>(&reinterpret_cast<ushort*>(out)[(size_t)n * DIM + lane * 4]) = pk;
    } else {
      *reinterpret_cast<float4*>(&out[(size_t)n * DIM + lane * 4]) = make_float4(o0, o1, o2, o3);
    }
  } else {
    float2 gg = *reinterpret_cast<const float2*>(&gamma[lane * 2]);
    float2 be = *reinterpret_cast<const float2*>(&beta[lane * 2]);
    float o0 = fmaxf((v[0] - mu) * rstd * gg.x + be.x, 0.f);
    float o1 = fmaxf((v[1] - mu) * rstd * gg.y + be.y, 0.f);
    if constexpr (BF16_OUT){
      uint pk = (uint)f2bf(o0) | ((uint)f2bf(o1) << 16);
      reinterpret_cast<uint*>(out)[(size_t)n * (DIM / 2) + lane] = pk;
    } else {
      *reinterpret_cast<float2*>(&out[(size_t)n * DIM + lane * 2]) = make_float2(o0, o1);
    }
  }
}

// ---------------- fused pooling + final projection (last-block-per-graph) ----------------
__global__ __launch_bounds__(128) void k_poolfin(const float* __restrict__ h, const int* __restrict__ pos,
    float* __restrict__ pool_sum, uint* __restrict__ pool_max, int* __restrict__ done,
    const float* __restrict__ Wp, const float* __restrict__ bp, float* __restrict__ out){
  const int c = (int)threadIdx.x;           // channel 0..127
  const int g = blockIdx.x >> 2;            // graph
  const int q = blockIdx.x & 3;             // quarter
  const int s = pos[g], e = pos[g + 1];
  const int len = e - s;
  if (len > 0){
    const int chunk = (len + 3) >> 2;
    const int n0 = s + q * chunk;
    const int n1 = min(n0 + chunk, e);
    if (n0 < n1){
      float sum = 0.f, mx = 0.f;            // post-ReLU values >= 0
      for (int n = n0; n < n1; n++){
        float v = h[(size_t)n * 128 + c];
        sum += v; mx = fmaxf(mx, v);
      }
      atomicAdd(&pool_sum[g * 128 + c], sum);
      atomicMax(&pool_max[g * 128 + c], __float_as_uint(mx));
    }
  }
  // done protocol: last of the 4 blocks for this graph computes the output row
  __threadfence();
  __syncthreads();
  __shared__ int old_s;
  if (c == 0) old_s = atomicAdd(&done[g], 1);
  __syncthreads();
  if (old_s == 3){
    __threadfence();
    float inv = 1.f / fmaxf((float)len, 1.f);
    float acc = bp[c];
    #pragma unroll 4
    for (int k = 0; k < 128; k++)
      acc = fmaf(pool_sum[g * 128 + k] * inv, Wp[k * 128 + c], acc);
    #pragma unroll 4
    for (int k = 0; k < 128; k++)
      acc = fmaf(__uint_as_float(pool_max[g * 128 + k]), Wp[(128 + k) * 128 + c], acc);
    out[g * 128 + c] = acc;
  }
}

// ---------------- launch ----------------
extern "C" void kernel_launch(void* const* d_in, const int* in_sizes, int n_in,
                              void* d_out, int out_size, void* d_ws, size_t ws_size,
                              hipStream_t stream){
  const float* x     = (const float*)d_in[0];
  const int*   ei    = (const int*)d_in[1];
  const int*   batch = (const int*)d_in[2];
  const float* W1    = (const float*)d_in[3];
  const float* asrc1 = (const float*)d_in[4];
  const float* adst1 = (const float*)d_in[5];
  const float* b1    = (const float*)d_in[6];
  const float* g1    = (const float*)d_in[7];
  const float* be1   = (const float*)d_in[8];
  const float* W2    = (const float*)d_in[9];
  const float* asrc2 = (const float*)d_in[10];
  const float* adst2 = (const float*)d_in[11];
  const float* b2    = (const float*)d_in[12];
  const float* g2    = (const float*)d_in[13];
  const float* be2   = (const float*)d_in[14];
  const float* W3    = (const float*)d_in[15];
  const float* asrc3 = (const float*)d_in[16];
  const float* adst3 = (const float*)d_in[17];
  const float* b3    = (const float*)d_in[18];
  const float* g3    = (const float*)d_in[19];
  const float* be3   = (const float*)d_in[20];
  const float* Wp    = (const float*)d_in[21];
  const float* bp    = (const float*)d_in[22];

  const int N = in_sizes[0] / 128;
  const int E = in_sizes[1] / 2;
  const int G = out_size / 128;
  const int EN = E + N;

  char* ws = (char*)d_ws;
  size_t off = 0;
  auto alloc = [&](size_t bytes) -> char* {
    char* p = ws + off;
    off = (off + bytes + 255) & ~(size_t)255;
    return p;
  };
  // region0: x_bf (N*128 bf16) lives here until aggw-L1 overwrites it with h_bf (N*256 bf16)
  ushort*   region0  = (ushort*)alloc((size_t)N * 256 * 2);
  ushort*   x_bf     = region0;
  ushort*   h_bf     = region0;
  ushort*   xbufA    = (ushort*)alloc((size_t)N * 256 * 2);  // xl (bf16)
  float*    xbufB    = (float*)alloc((size_t)N * 128 * 4);   // layer-3 output (f32, pooling)
  float*    al       = (float*)alloc((size_t)N * 4 * 4);
  float*    ar       = (float*)alloc((size_t)N * 4 * 4);
  int*      deg      = (int*)alloc((size_t)N * 4);
  int*      row_ptr  = (int*)alloc((size_t)(N + 1) * 4);
  int*      cursor   = (int*)alloc((size_t)N * 4);
  int*      csr_src  = (int*)alloc((size_t)EN * 4);
  int*      pos      = (int*)alloc((size_t)(G + 1) * 4);
  float*    pool_sum = (float*)alloc((size_t)G * 128 * 4);
  uint*     pool_max = (uint*)alloc((size_t)G * 128 * 4);
  int*      done     = (int*)alloc((size_t)G * 4);
  ushort*   W1t      = (ushort*)alloc((size_t)256 * 128 * 2);  // [N=256][K=128]
  ushort*   W2t      = (ushort*)alloc((size_t)256 * 256 * 2);  // [256][256]
  ushort*   W3t      = (ushort*)alloc((size_t)128 * 256 * 2);  // [128][256]
  const int NB = (N + 1023) / 1024;
  int*      pref     = (int*)alloc((size_t)NB * 4);
  int*      flag     = (int*)alloc((size_t)NB * 4);

  hipMemsetAsync(deg, 0, (size_t)N * 4, stream);

  // mega-prep (cast/transpose/deg/bounds/zeroing) -> scan -> scatter
  {
    int total = N * 32 + 256 * 128 + 256 * 256 + 128 * 256 + EN + G * 128;
    k_prep<<<(total + 255) / 256, 256, 0, stream>>>(x, x_bf, W1, W1t, W2, W2t, W3, W3t,
                                                    ei, deg, batch, pos,
                                                    pool_sum, pool_max, done, flag,
                                                    N, E, G, NB);
  }
  k_scanall<<<NB, 1024, 0, stream>>>(deg, row_ptr, cursor, pref, flag, N);
  k_scatter<<<(EN + 255) / 256, 256, 0, stream>>>(ei, cursor, csr_src, E, N);

  const int MB = (N + 127) / 128;
  const int NB4 = (N + 3) / 4;

  // Layer 1: 128 -> 256, H=4, C=64
  k_mm<128, 256, 4><<<dim3(MB, 2), 256, 0, stream>>>(x_bf, W1t, xbufA, asrc1, adst1, al, ar, N);
  k_aggw<4, 256, true><<<NB4, 256, 0, stream>>>(xbufA, al, ar, row_ptr, csr_src, b1, g1, be1, (float*)h_bf, N);

  // Layer 2: 256 -> 256, H=4, C=64
  k_mm<256, 256, 4><<<dim3(MB, 2), 256, 0, stream>>>(h_bf, W2t, xbufA, asrc2, adst2, al, ar, N);
  k_aggw<4, 256, true><<<NB4, 256, 0, stream>>>(xbufA, al, ar, row_ptr, csr_src, b2, g2, be2, (float*)h_bf, N);

  // Layer 3: 256 -> 128, H=1, C=128
  k_mm<256, 128, 1><<<dim3(MB, 1), 256, 0, stream>>>(h_bf, W3t, xbufA, asrc3, adst3, al, ar, N);
  k_aggw<1, 128, false><<<NB4, 256, 0, stream>>>(xbufA, al, ar, row_ptr, csr_src, b3, g3, be3, xbufB, N);

  // Fused pooling + final projection
  k_poolfin<<<G * 4, 128, 0, stream>>>(xbufB, pos, pool_sum, pool_max, done, Wp, bp, (float*)d_out);
}